// Round 13
// baseline (171.832 us; speedup 1.0000x reference)
//
#include <hip/hip_runtime.h>
#include <hip/hip_bf16.h>
#include <stdint.h>
#include <math.h>

typedef __bf16 bf16_t;
typedef __bf16 bf16x8 __attribute__((ext_vector_type(8)));
typedef float  f32x4  __attribute__((ext_vector_type(4)));
typedef float  f32x16 __attribute__((ext_vector_type(16)));
typedef unsigned int u32;

#define S_SZ 4096
#define HS   64
#define OUT_B_STRIDE (256 * 64 * 64)
#define LOG2E 1.4426950408889634f

// async global->LDS, 16B per lane, dest = wave-uniform base + lane*16
#define GLOAD_LDS(gsrc, ldst)                                                              \
    __builtin_amdgcn_global_load_lds((__attribute__((address_space(1))) void*)(void*)(gsrc), \
                                     (__attribute__((address_space(3))) void*)(void*)(ldst),  \
                                     16, 0, 0)

static __device__ __forceinline__ u32 pack2(__bf16 a, __bf16 b) {
    return (u32)__builtin_bit_cast(uint16_t, a) | ((u32)__builtin_bit_cast(uint16_t, b) << 16);
}

// =======================================================================================
// prep: blocks 0..47: W -> bf16 hi/lo (Q rows pre-scaled by log2e), coalesced.
//       blocks 48..111: R[n][t][d] = rel_h + rel_w (bf16), t = h2*256 + o, LDS-staged.
// =======================================================================================
__global__ __launch_bounds__(256)
void prep_kernel(const float* __restrict__ wq, const float* __restrict__ wk,
                 const float* __restrict__ wv, const float* __restrict__ rel_h,
                 const float* __restrict__ rel_w,
                 bf16_t* __restrict__ Wh, bf16_t* __restrict__ Wl,
                 bf16_t* __restrict__ Rt)
{
    const int blk = blockIdx.x;
    if (blk < 48) {
        const int base = blk * 4096;
        #pragma unroll
        for (int i = 0; i < 16; ++i) {
            const int e = base + i * 256 + threadIdx.x;
            const int o = e >> 8, c = e & 255;
            const float* src = o < 256 ? wq : (o < 512 ? wk : wv);
            float v = src[(size_t)(o & 255) * 256 + c];
            if (o < 256) v *= LOG2E;
            __bf16 h = (__bf16)v;
            Wh[e] = h;
            Wl[e] = (__bf16)(v - (float)h);
        }
    } else {
        const int rb = blk - 48;
        const int n = rb >> 4, h2 = rb & 15;
        __shared__ float rh[4096], rw[4096];
        for (int i = threadIdx.x; i < 4096; i += 256) {
            rh[i] = rel_h[n * 4096 + i];
            rw[i] = rel_w[n * 4096 + i];
        }
        __syncthreads();
        bf16_t* Rp = Rt + ((size_t)n * 4096 + h2 * 256) * 64;
        const int d0 = (threadIdx.x & 7) * 8;
        const int ob = threadIdx.x >> 3;
        #pragma unroll
        for (int i = 0; i < 8; ++i) {
            const int o  = i * 32 + ob;
            const int ih = (o & 3) * 16 + h2;
            const int iw = o >> 2;
            bf16x8 rv;
            #pragma unroll
            for (int dd = 0; dd < 8; ++dd)
                rv[dd] = (bf16_t)(rh[(d0 + dd) * 64 + ih] + rw[(d0 + dd) * 64 + iw]);
            *(bf16x8*)(Rp + (size_t)o * 64 + d0) = rv;
        }
    }
}

// =======================================================================================
// proj (64KB LDS): bf16 MFMA, 3-product hi/lo split, W register double-buffer,
// two-pass coalesced epilogue. grid 256, block 512 (8 waves). (unchanged from R9)
// =======================================================================================
__global__ __launch_bounds__(512, 2)
void proj_kernel(const float* __restrict__ x,
                 const bf16_t* __restrict__ Wh, const bf16_t* __restrict__ Wl,
                 const float* __restrict__ bq, const float* __restrict__ bk,
                 const float* __restrict__ bv, const bf16_t* __restrict__ Rt,
                 bf16_t* __restrict__ q_ws, bf16_t* __restrict__ k2_ws,
                 bf16_t* __restrict__ vt2_ws)
{
    const int bx = blockIdx.x;
    const int b  = bx >> 6;
    const int h  = bx & 63;
    const int p0 = h * 64;
    const int n  = h & 3;
    const int h2 = h >> 2;
    const int bn = b * 4 + n;
    const int tid = threadIdx.x;

    __shared__ __align__(16) char SM[65536];

    {
        const int cpair = tid & 127, pg = tid >> 7;
        const int c0 = cpair * 2;
        const float* x0 = x + ((size_t)b * 256 + c0) * 4096 + p0 + pg * 16;
        const int sub = (c0 >> 6) * 128;
        const int u   = (c0 >> 3) & 7;
        const int e2  = (c0 & 7) * 2;
        #pragma unroll
        for (int i4 = 0; i4 < 4; ++i4) {
            f32x4 ra = *(const f32x4*)(x0 + i4 * 4);
            f32x4 rb = *(const f32x4*)(x0 + 4096 + i4 * 4);
            #pragma unroll
            for (int i = 0; i < 4; ++i) {
                const int p = pg * 16 + i4 * 4 + i;
                __bf16 ha = (__bf16)ra[i], hb = (__bf16)rb[i];
                float  la = ra[i] - (float)ha, lb = rb[i] - (float)hb;
                const int off = p * 512 + sub + ((u ^ (p & 7)) * 16) + e2;
                *(u32*)(SM + off)         = pack2(ha, hb);
                *(u32*)(SM + 32768 + off) = pack2((__bf16)la, (__bf16)lb);
            }
        }
    }
    __syncthreads();

    const int wid = tid >> 6, lane = tid & 63, l31 = lane & 31, hi = lane >> 5;

    int obs[3], pjs[3];
    const bf16_t* whp[3];
    const bf16_t* wlp[3];
    #pragma unroll
    for (int j = 0; j < 3; ++j) {
        const int of = (wid * 3 + j) * 32;
        pjs[j] = of >> 8;
        obs[j] = of & 255;
        whp[j] = Wh + (size_t)(of + l31) * 256 + hi * 8;
        wlp[j] = Wl + (size_t)(of + l31) * 256 + hi * 8;
    }

    const char* XHp = SM + l31 * 512;
    const char* XLp = SM + 32768 + l31 * 512;

    f32x16 acc[3][2] = {};

    bf16x8 whC[3], wlC[3], whN[3], wlN[3];
    #pragma unroll
    for (int j = 0; j < 3; ++j) {
        whC[j] = *(const bf16x8*)(whp[j]);
        wlC[j] = *(const bf16x8*)(wlp[j]);
    }

    #pragma unroll
    for (int ks = 0; ks < 16; ++ks) {
        if (ks < 15) {
            #pragma unroll
            for (int j = 0; j < 3; ++j) {
                whN[j] = *(const bf16x8*)(whp[j] + (ks + 1) * 16);
                wlN[j] = *(const bf16x8*)(wlp[j] + (ks + 1) * 16);
            }
        }
        const int rb_ = (ks >> 2) * 128 + ((((ks * 2 + hi) & 7) ^ (l31 & 7)) * 16);
        bf16x8 xh[2], xl[2];
        #pragma unroll
        for (int pt = 0; pt < 2; ++pt) {
            xh[pt] = *(const bf16x8*)(XHp + pt * 16384 + rb_);
            xl[pt] = *(const bf16x8*)(XLp + pt * 16384 + rb_);
        }
        #pragma unroll
        for (int j = 0; j < 3; ++j)
            #pragma unroll
            for (int pt = 0; pt < 2; ++pt) {
                acc[j][pt] = __builtin_amdgcn_mfma_f32_32x32x16_bf16(whC[j], xh[pt], acc[j][pt], 0, 0, 0);
                acc[j][pt] = __builtin_amdgcn_mfma_f32_32x32x16_bf16(whC[j], xl[pt], acc[j][pt], 0, 0, 0);
                acc[j][pt] = __builtin_amdgcn_mfma_f32_32x32x16_bf16(wlC[j], xh[pt], acc[j][pt], 0, 0, 0);
            }
        #pragma unroll
        for (int j = 0; j < 3; ++j) { whC[j] = whN[j]; wlC[j] = wlN[j]; }
    }
    __syncthreads();

    f32x4 bias[3][2][4];
    #pragma unroll
    for (int j = 0; j < 3; ++j) {
        const float* bp = pjs[j] == 0 ? bq : (pjs[j] == 1 ? bk : bv);
        #pragma unroll
        for (int g2 = 0; g2 < 4; ++g2) {
            f32x4 v = *(const f32x4*)(bp + obs[j] + hi * 4 + g2 * 8);
            if (pjs[j] == 0) {
                #pragma unroll
                for (int i = 0; i < 4; ++i) v[i] *= LOG2E;
            }
            bias[j][0][g2] = v;  bias[j][1][g2] = v;
        }
    }

    // pass 1: Q -> [0,32K), V -> [32,64K)
    #pragma unroll
    for (int j = 0; j < 3; ++j) {
        if (pjs[j] == 1) continue;
        #pragma unroll
        for (int pt = 0; pt < 2; ++pt) {
            const int d = pt * 32 + l31;
            #pragma unroll
            for (int g2 = 0; g2 < 4; ++g2)
                #pragma unroll
                for (int rr = 0; rr < 4; ++rr) {
                    const int o = obs[j] + rr + 4 * hi + 8 * g2;
                    const float v = acc[j][pt][g2 * 4 + rr] + bias[j][pt][g2][rr];
                    if (pjs[j] == 0) {
                        *(bf16_t*)(SM + o * 128 + d * 2) = (bf16_t)v;
                    } else {
                        *(bf16_t*)(SM + 32768 + d * 512 + ((o * 2) ^ ((d & 7) << 4))) = (bf16_t)v;
                    }
                }
        }
    }
    __syncthreads();
    {
        bf16_t* qp = q_ws + (size_t)bn * 4096 * 64;
        #pragma unroll
        for (int i = 0; i < 4; ++i) {
            const int c = i * 512 + tid;
            const int o = c >> 3, d8 = c & 7;
            uint4 v = *(const uint4*)(SM + c * 16);
            *(uint4*)(qp + (size_t)(o * 16 + h2) * 64 + d8 * 8) = v;
        }
        bf16_t* vp = vt2_ws + (size_t)bn * 64 * 4096 + h2 * 256;
        #pragma unroll
        for (int i = 0; i < 4; ++i) {
            const int c = i * 512 + tid;
            const int d = c >> 5, k = c & 31;
            uint4 v = *(const uint4*)(SM + 32768 + d * 512 + ((k * 16) ^ ((d & 7) << 4)));
            *(uint4*)(vp + (size_t)d * 4096 + k * 8) = v;
        }
    }
    __syncthreads();

    // pass 2: K -> [0,32K)
    #pragma unroll
    for (int j = 0; j < 3; ++j) {
        if (pjs[j] != 1) continue;
        #pragma unroll
        for (int pt = 0; pt < 2; ++pt) {
            const int d = pt * 32 + l31;
            #pragma unroll
            for (int g2 = 0; g2 < 4; ++g2)
                #pragma unroll
                for (int rr = 0; rr < 4; ++rr) {
                    const int o = obs[j] + rr + 4 * hi + 8 * g2;
                    *(bf16_t*)(SM + o * 128 + d * 2) =
                        (bf16_t)(acc[j][pt][g2 * 4 + rr] + bias[j][pt][g2][rr]);
                }
        }
    }
    __syncthreads();
    {
        const bf16_t* Rp = Rt + ((size_t)n * 4096 + h2 * 256) * 64;
        bf16_t* kp = k2_ws + ((size_t)bn * 4096 + h2 * 256) * 64;
        #pragma unroll
        for (int i = 0; i < 4; ++i) {
            const int c = i * 512 + tid;
            bf16x8 kv = *(const bf16x8*)(SM + c * 16);
            bf16x8 rv = *(const bf16x8*)(Rp + c * 8);
            bf16x8 res;
            #pragma unroll
            for (int ii = 0; ii < 8; ++ii)
                res[ii] = (__bf16)((float)kv[ii] + (float)rv[ii]);
            *(bf16x8*)(kp + c * 8) = res;
        }
    }
}

// =======================================================================================
// flash attention v6: 2-wave blocks (128 q), full 64-tile KV range, no split/combine.
// grid 512 = 16 bn x 32 qb, block 128, ring-2 32KB LDS -> 4 blocks/CU = 2 waves/SIMD
// from independent blocks. 64 q/wave TILE (32 MFMA per 16 ds_read_b128), normalized
// output in-kernel.
// =======================================================================================
__global__ __launch_bounds__(128, 2)
void attn_kernel(const bf16_t* __restrict__ q_ws, const bf16_t* __restrict__ k_ws,
                 const bf16_t* __restrict__ vt_ws, float* __restrict__ out)
{
    const int tid  = threadIdx.x;
    const int wid  = tid >> 6;
    const int lane = tid & 63;
    const int l31  = lane & 31;
    const int hi   = lane >> 5;

    // bijective XCD swizzle: 512 blocks, 64/XCD = 2 bn per XCD (K/V L2-resident)
    const int wg  = blockIdx.x;
    const int swz = (wg & 7) * 64 + (wg >> 3);
    const int bn  = swz >> 5;
    const int qb  = swz & 31;
    const int b   = bn >> 2, n = bn & 3;

    __shared__ __align__(16) bf16_t Kt[2][64 * 64];   // ring-2, XOR-swizzled 16B units
    __shared__ __align__(16) bf16_t Vt[2][64 * 64];

    const bf16_t* Qb = q_ws  + (size_t)bn * S_SZ * HS;
    const bf16_t* Kb = k_ws  + (size_t)bn * S_SZ * HS;
    const bf16_t* Vb = vt_ws + (size_t)bn * HS * S_SZ;

    // staging: 512 16B-chunks per 8KB tile over 128 threads = 4 K + 4 V chunks/thread
    const bf16_t* ksrc[4];
    const bf16_t* vsrc[4];
    int dstoff[4];
    #pragma unroll
    for (int i = 0; i < 4; ++i) {
        const int c = wid * 64 + i * 128 + lane;
        const int row = c >> 3, ga = (c & 7) ^ (row & 7);
        ksrc[i] = Kb + (size_t)row * HS + ga * 8;
        vsrc[i] = Vb + (size_t)row * S_SZ + ga * 8;
        dstoff[i] = (wid * 64 + i * 128) * 8;    // bf16 elements (wave-uniform)
    }

#define STAGE(buf, ts)                                                        \
    { _Pragma("unroll")                                                       \
      for (int i_ = 0; i_ < 4; ++i_)                                          \
          GLOAD_LDS(ksrc[i_] + (size_t)(ts) * 64 * HS, &Kt[buf][dstoff[i_]]); \
      _Pragma("unroll")                                                       \
      for (int i_ = 0; i_ < 4; ++i_)                                          \
          GLOAD_LDS(vsrc[i_] + (ts) * 64, &Vt[buf][dstoff[i_]]); }

    // 64 q per wave: two q-halves q0 = base, q1 = base+32
    const int q0 = qb * 128 + wid * 64 + l31;
    bf16x8 qf0[4], qf1[4];
    #pragma unroll
    for (int dk = 0; dk < 4; ++dk) {
        qf0[dk] = *(const bf16x8*)(Qb + (size_t)q0 * HS + dk * 16 + hi * 8);
        qf1[dk] = *(const bf16x8*)(Qb + (size_t)(q0 + 32) * HS + dk * 16 + hi * 8);
    }

    f32x16 oacc[2][2];   // [dh][qh]
    f32x16 Z16;
    #pragma unroll
    for (int i = 0; i < 16; ++i) {
        oacc[0][0][i] = 0.f; oacc[0][1][i] = 0.f;
        oacc[1][0][i] = 0.f; oacc[1][1][i] = 0.f;
        Z16[i] = 0.f;
    }
    float lsum0 = 0.f, lsum1 = 0.f;

    const int swzme = (l31 & 7) << 4;

#define TILE(BUF)                                                                      \
    { const char* Kb_ = (const char*)&Kt[BUF][0] + l31 * 128;                          \
      const char* Vb_ = (const char*)&Vt[BUF][0] + l31 * 128;                          \
      f32x16 sacc[2][2];                                                               \
      _Pragma("unroll")                                                                \
      for (int hh = 0; hh < 2; ++hh) {                                                 \
          bf16x8 kf[4];                                                                \
          _Pragma("unroll")                                                            \
          for (int dk = 0; dk < 4; ++dk)                                               \
              kf[dk] = *(const bf16x8*)(Kb_ + hh * 4096 + (((2 * dk + hi) * 16) ^ swzme)); \
          sacc[hh][0] = __builtin_amdgcn_mfma_f32_32x32x16_bf16(kf[0], qf0[0], Z16, 0, 0, 0); \
          sacc[hh][1] = __builtin_amdgcn_mfma_f32_32x32x16_bf16(kf[0], qf1[0], Z16, 0, 0, 0); \
          _Pragma("unroll")                                                            \
          for (int dk = 1; dk < 4; ++dk) {                                             \
              sacc[hh][0] = __builtin_amdgcn_mfma_f32_32x32x16_bf16(kf[dk], qf0[dk], sacc[hh][0], 0, 0, 0); \
              sacc[hh][1] = __builtin_amdgcn_mfma_f32_32x32x16_bf16(kf[dk], qf1[dk], sacc[hh][1], 0, 0, 0); \
          }                                                                            \
      }                                                                                \
      u32 F0[4][4], F1[4][4];                                                          \
      { u32 Wd[2][4][2];                                                               \
        float ps[4] = {0.f, 0.f, 0.f, 0.f};                                            \
        _Pragma("unroll")                                                              \
        for (int hh = 0; hh < 2; ++hh)                                                 \
        _Pragma("unroll")                                                              \
        for (int c = 0; c < 4; ++c)                                                    \
        _Pragma("unroll")                                                              \
        for (int tt = 0; tt < 2; ++tt) {                                               \
            float pa = __builtin_amdgcn_exp2f(sacc[hh][0][c * 4 + tt * 2]);            \
            float pb = __builtin_amdgcn_exp2f(sacc[hh][0][c * 4 + tt * 2 + 1]);        \
            ps[c] += pa + pb;                                                          \
            u32 w_;                                                                    \
            asm("v_cvt_pk_bf16_f32 %0, %1, %2" : "=v"(w_) : "v"(pa), "v"(pb));         \
            Wd[hh][c][tt] = w_; }                                                      \
        lsum0 += (ps[0] + ps[1]) + (ps[2] + ps[3]);                                    \
        _Pragma("unroll")                                                              \
        for (int hh = 0; hh < 2; ++hh)                                                 \
        _Pragma("unroll")                                                              \
        for (int pr = 0; pr < 2; ++pr)                                                 \
        _Pragma("unroll")                                                              \
        for (int tt = 0; tt < 2; ++tt) {                                               \
            u32 a_ = Wd[hh][2 * pr][tt], b_ = Wd[hh][2 * pr + 1][tt];                  \
            asm("v_permlane32_swap_b32 %0, %1" : "+v"(a_), "+v"(b_));                  \
            F0[2 * hh + pr][tt]     = a_;                                              \
            F0[2 * hh + pr][2 + tt] = b_; } }                                          \
      { u32 Wd[2][4][2];                                                               \
        float ps[4] = {0.f, 0.f, 0.f, 0.f};                                            \
        _Pragma("unroll")                                                              \
        for (int hh = 0; hh < 2; ++hh)                                                 \
        _Pragma("unroll")                                                              \
        for (int c = 0; c < 4; ++c)                                                    \
        _Pragma("unroll")                                                              \
        for (int tt = 0; tt < 2; ++tt) {                                               \
            float pa = __builtin_amdgcn_exp2f(sacc[hh][1][c * 4 + tt * 2]);            \
            float pb = __builtin_amdgcn_exp2f(sacc[hh][1][c * 4 + tt * 2 + 1]);        \
            ps[c] += pa + pb;                                                          \
            u32 w_;                                                                    \
            asm("v_cvt_pk_bf16_f32 %0, %1, %2" : "=v"(w_) : "v"(pa), "v"(pb));         \
            Wd[hh][c][tt] = w_; }                                                      \
        lsum1 += (ps[0] + ps[1]) + (ps[2] + ps[3]);                                    \
        _Pragma("unroll")                                                              \
        for (int hh = 0; hh < 2; ++hh)                                                 \
        _Pragma("unroll")                                                              \
        for (int pr = 0; pr < 2; ++pr)                                                 \
        _Pragma("unroll")                                                              \
        for (int tt = 0; tt < 2; ++tt) {                                               \
            u32 a_ = Wd[hh][2 * pr][tt], b_ = Wd[hh][2 * pr + 1][tt];                  \
            asm("v_permlane32_swap_b32 %0, %1" : "+v"(a_), "+v"(b_));                  \
            F1[2 * hh + pr][tt]     = a_;                                              \
            F1[2 * hh + pr][2 + tt] = b_; } }                                          \
      _Pragma("unroll")                                                                \
      for (int dh = 0; dh < 2; ++dh)                                                   \
      _Pragma("unroll")                                                                \
      for (int kk = 0; kk < 4; ++kk) {                                                 \
          bf16x8 vf = *(const bf16x8*)(Vb_ + dh * 4096 + (((2 * kk + hi) * 16) ^ swzme)); \
          union { u32 u[4]; bf16x8 v; } p0, p1;                                        \
          p0.u[0] = F0[kk][0]; p0.u[1] = F0[kk][1]; p0.u[2] = F0[kk][2]; p0.u[3] = F0[kk][3]; \
          p1.u[0] = F1[kk][0]; p1.u[1] = F1[kk][1]; p1.u[2] = F1[kk][2]; p1.u[3] = F1[kk][3]; \
          oacc[dh][0] = __builtin_amdgcn_mfma_f32_32x32x16_bf16(vf, p0.v, oacc[dh][0], 0, 0, 0); \
          oacc[dh][1] = __builtin_amdgcn_mfma_f32_32x32x16_bf16(vf, p1.v, oacc[dh][1], 0, 0, 0); } }

    // ring-2, depth-1 (proven R8/R12 loop), full 64-tile range
    STAGE(0, 0);
    asm volatile("s_waitcnt vmcnt(0)" ::: "memory");
    __builtin_amdgcn_s_barrier();
    asm volatile("" ::: "memory");
    for (int t = 0; t < 64; t += 2) {
        { const int ts = (t + 1 < 64) ? t + 1 : 63; STAGE(1, ts); }
        TILE(0);
        asm volatile("s_waitcnt vmcnt(0)" ::: "memory");
        __builtin_amdgcn_s_barrier();
        asm volatile("" ::: "memory");
        { const int ts = (t + 2 < 64) ? t + 2 : 63; STAGE(0, ts); }
        TILE(1);
        asm volatile("s_waitcnt vmcnt(0)" ::: "memory");
        __builtin_amdgcn_s_barrier();
        asm volatile("" ::: "memory");
    }
#undef TILE
#undef STAGE

    // ---- epilogue: normalized, two q rows per lane ----
    float lt0 = lsum0 + __shfl_xor(lsum0, 32);
    float lt1 = lsum1 + __shfl_xor(lsum1, 32);
    float inv0 = 1.0f / lt0;
    float inv1 = 1.0f / lt1;
    float* outp0 = out + (size_t)b * OUT_B_STRIDE + (size_t)q0 * 256 + n * 64;
    float* outp1 = outp0 + 32 * 256;
    #pragma unroll
    for (int dh = 0; dh < 2; ++dh)
        #pragma unroll
        for (int g2 = 0; g2 < 4; ++g2) {
            f32x4 v4, w4;
            #pragma unroll
            for (int r2 = 0; r2 < 4; ++r2) {
                v4[r2] = oacc[dh][0][g2 * 4 + r2] * inv0;
                w4[r2] = oacc[dh][1][g2 * 4 + r2] * inv1;
            }
            *(f32x4*)(outp0 + dh * 32 + g2 * 8 + hi * 4) = v4;
            *(f32x4*)(outp1 + dh * 32 + g2 * 8 + hi * 4) = w4;
        }
}

extern "C" void kernel_launch(void* const* d_in, const int* in_sizes, int n_in,
                              void* d_out, int out_size, void* d_ws, size_t ws_size,
                              hipStream_t stream)
{
    const float* x     = (const float*)d_in[0];
    const float* wq    = (const float*)d_in[1];
    const float* bq    = (const float*)d_in[2];
    const float* wk    = (const float*)d_in[3];
    const float* bk    = (const float*)d_in[4];
    const float* wv    = (const float*)d_in[5];
    const float* bv    = (const float*)d_in[6];
    const float* rel_h = (const float*)d_in[7];
    const float* rel_w = (const float*)d_in[8];
    float* out = (float*)d_out;

    bf16_t* q_ws   = (bf16_t*)d_ws;
    bf16_t* k2_ws  = q_ws  + (size_t)16 * S_SZ * HS;
    bf16_t* vt2_ws = k2_ws + (size_t)16 * S_SZ * HS;

    // scratch in d_out's tail (dead after proj; attn overwrites all of out)
    bf16_t* end = (bf16_t*)d_out + (size_t)out_size * 2;
    bf16_t* Wl  = end - 196608;
    bf16_t* Wh  = Wl - 196608;
    bf16_t* Rt  = Wh - 1048576;

    prep_kernel<<<112, 256, 0, stream>>>(wq, wk, wv, rel_h, rel_w, Wh, Wl, Rt);
    proj_kernel<<<256, 512, 0, stream>>>(x, Wh, Wl, bq, bk, bv, Rt,
                                         q_ws, k2_ws, vt2_ws);
    attn_kernel<<<512, 128, 0, stream>>>(q_ws, k2_ws, vt2_ws, out);
}

// Round 14
// 130.589 us; speedup vs baseline: 1.3158x; 1.3158x over previous
//
#include <hip/hip_runtime.h>
#include <hip/hip_bf16.h>
#include <stdint.h>
#include <math.h>

typedef __bf16 bf16_t;
typedef __bf16 bf16x8 __attribute__((ext_vector_type(8)));
typedef float  f32x4  __attribute__((ext_vector_type(4)));
typedef float  f32x16 __attribute__((ext_vector_type(16)));
typedef unsigned int u32;

#define S_SZ 4096
#define HS   64
#define OUT_B_STRIDE (256 * 64 * 64)
#define LOG2E 1.4426950408889634f

// async global->LDS, 16B per lane, dest = wave-uniform base + lane*16
#define GLOAD_LDS(gsrc, ldst)                                                              \
    __builtin_amdgcn_global_load_lds((__attribute__((address_space(1))) void*)(void*)(gsrc), \
                                     (__attribute__((address_space(3))) void*)(void*)(ldst),  \
                                     16, 0, 0)

static __device__ __forceinline__ u32 pack2(__bf16 a, __bf16 b) {
    return (u32)__builtin_bit_cast(uint16_t, a) | ((u32)__builtin_bit_cast(uint16_t, b) << 16);
}

// =======================================================================================
// prep: blocks 0..47: W -> bf16 hi/lo (Q rows pre-scaled by log2e), coalesced.
//       blocks 48..111: R[n][t][d] = rel_h + rel_w (bf16), t = h2*256 + o, LDS-staged.
// =======================================================================================
__global__ __launch_bounds__(256)
void prep_kernel(const float* __restrict__ wq, const float* __restrict__ wk,
                 const float* __restrict__ wv, const float* __restrict__ rel_h,
                 const float* __restrict__ rel_w,
                 bf16_t* __restrict__ Wh, bf16_t* __restrict__ Wl,
                 bf16_t* __restrict__ Rt)
{
    const int blk = blockIdx.x;
    if (blk < 48) {
        const int base = blk * 4096;
        #pragma unroll
        for (int i = 0; i < 16; ++i) {
            const int e = base + i * 256 + threadIdx.x;
            const int o = e >> 8, c = e & 255;
            const float* src = o < 256 ? wq : (o < 512 ? wk : wv);
            float v = src[(size_t)(o & 255) * 256 + c];
            if (o < 256) v *= LOG2E;
            __bf16 h = (__bf16)v;
            Wh[e] = h;
            Wl[e] = (__bf16)(v - (float)h);
        }
    } else {
        const int rb = blk - 48;
        const int n = rb >> 4, h2 = rb & 15;
        __shared__ float rh[4096], rw[4096];
        for (int i = threadIdx.x; i < 4096; i += 256) {
            rh[i] = rel_h[n * 4096 + i];
            rw[i] = rel_w[n * 4096 + i];
        }
        __syncthreads();
        bf16_t* Rp = Rt + ((size_t)n * 4096 + h2 * 256) * 64;
        const int d0 = (threadIdx.x & 7) * 8;
        const int ob = threadIdx.x >> 3;
        #pragma unroll
        for (int i = 0; i < 8; ++i) {
            const int o  = i * 32 + ob;
            const int ih = (o & 3) * 16 + h2;
            const int iw = o >> 2;
            bf16x8 rv;
            #pragma unroll
            for (int dd = 0; dd < 8; ++dd)
                rv[dd] = (bf16_t)(rh[(d0 + dd) * 64 + ih] + rw[(d0 + dd) * 64 + iw]);
            *(bf16x8*)(Rp + (size_t)o * 64 + d0) = rv;
        }
    }
}

// =======================================================================================
// proj (64KB LDS): bf16 MFMA, 3-product hi/lo split, W register double-buffer,
// two-pass coalesced epilogue. grid 256, block 512 (8 waves). (unchanged from R9)
// =======================================================================================
__global__ __launch_bounds__(512, 2)
void proj_kernel(const float* __restrict__ x,
                 const bf16_t* __restrict__ Wh, const bf16_t* __restrict__ Wl,
                 const float* __restrict__ bq, const float* __restrict__ bk,
                 const float* __restrict__ bv, const bf16_t* __restrict__ Rt,
                 bf16_t* __restrict__ q_ws, bf16_t* __restrict__ k2_ws,
                 bf16_t* __restrict__ vt2_ws)
{
    const int bx = blockIdx.x;
    const int b  = bx >> 6;
    const int h  = bx & 63;
    const int p0 = h * 64;
    const int n  = h & 3;
    const int h2 = h >> 2;
    const int bn = b * 4 + n;
    const int tid = threadIdx.x;

    __shared__ __align__(16) char SM[65536];

    {
        const int cpair = tid & 127, pg = tid >> 7;
        const int c0 = cpair * 2;
        const float* x0 = x + ((size_t)b * 256 + c0) * 4096 + p0 + pg * 16;
        const int sub = (c0 >> 6) * 128;
        const int u   = (c0 >> 3) & 7;
        const int e2  = (c0 & 7) * 2;
        #pragma unroll
        for (int i4 = 0; i4 < 4; ++i4) {
            f32x4 ra = *(const f32x4*)(x0 + i4 * 4);
            f32x4 rb = *(const f32x4*)(x0 + 4096 + i4 * 4);
            #pragma unroll
            for (int i = 0; i < 4; ++i) {
                const int p = pg * 16 + i4 * 4 + i;
                __bf16 ha = (__bf16)ra[i], hb = (__bf16)rb[i];
                float  la = ra[i] - (float)ha, lb = rb[i] - (float)hb;
                const int off = p * 512 + sub + ((u ^ (p & 7)) * 16) + e2;
                *(u32*)(SM + off)         = pack2(ha, hb);
                *(u32*)(SM + 32768 + off) = pack2((__bf16)la, (__bf16)lb);
            }
        }
    }
    __syncthreads();

    const int wid = tid >> 6, lane = tid & 63, l31 = lane & 31, hi = lane >> 5;

    int obs[3], pjs[3];
    const bf16_t* whp[3];
    const bf16_t* wlp[3];
    #pragma unroll
    for (int j = 0; j < 3; ++j) {
        const int of = (wid * 3 + j) * 32;
        pjs[j] = of >> 8;
        obs[j] = of & 255;
        whp[j] = Wh + (size_t)(of + l31) * 256 + hi * 8;
        wlp[j] = Wl + (size_t)(of + l31) * 256 + hi * 8;
    }

    const char* XHp = SM + l31 * 512;
    const char* XLp = SM + 32768 + l31 * 512;

    f32x16 acc[3][2] = {};

    bf16x8 whC[3], wlC[3], whN[3], wlN[3];
    #pragma unroll
    for (int j = 0; j < 3; ++j) {
        whC[j] = *(const bf16x8*)(whp[j]);
        wlC[j] = *(const bf16x8*)(wlp[j]);
    }

    #pragma unroll
    for (int ks = 0; ks < 16; ++ks) {
        if (ks < 15) {
            #pragma unroll
            for (int j = 0; j < 3; ++j) {
                whN[j] = *(const bf16x8*)(whp[j] + (ks + 1) * 16);
                wlN[j] = *(const bf16x8*)(wlp[j] + (ks + 1) * 16);
            }
        }
        const int rb_ = (ks >> 2) * 128 + ((((ks * 2 + hi) & 7) ^ (l31 & 7)) * 16);
        bf16x8 xh[2], xl[2];
        #pragma unroll
        for (int pt = 0; pt < 2; ++pt) {
            xh[pt] = *(const bf16x8*)(XHp + pt * 16384 + rb_);
            xl[pt] = *(const bf16x8*)(XLp + pt * 16384 + rb_);
        }
        #pragma unroll
        for (int j = 0; j < 3; ++j)
            #pragma unroll
            for (int pt = 0; pt < 2; ++pt) {
                acc[j][pt] = __builtin_amdgcn_mfma_f32_32x32x16_bf16(whC[j], xh[pt], acc[j][pt], 0, 0, 0);
                acc[j][pt] = __builtin_amdgcn_mfma_f32_32x32x16_bf16(whC[j], xl[pt], acc[j][pt], 0, 0, 0);
                acc[j][pt] = __builtin_amdgcn_mfma_f32_32x32x16_bf16(wlC[j], xh[pt], acc[j][pt], 0, 0, 0);
            }
        #pragma unroll
        for (int j = 0; j < 3; ++j) { whC[j] = whN[j]; wlC[j] = wlN[j]; }
    }
    __syncthreads();

    f32x4 bias[3][2][4];
    #pragma unroll
    for (int j = 0; j < 3; ++j) {
        const float* bp = pjs[j] == 0 ? bq : (pjs[j] == 1 ? bk : bv);
        #pragma unroll
        for (int g2 = 0; g2 < 4; ++g2) {
            f32x4 v = *(const f32x4*)(bp + obs[j] + hi * 4 + g2 * 8);
            if (pjs[j] == 0) {
                #pragma unroll
                for (int i = 0; i < 4; ++i) v[i] *= LOG2E;
            }
            bias[j][0][g2] = v;  bias[j][1][g2] = v;
        }
    }

    // pass 1: Q -> [0,32K), V -> [32,64K)
    #pragma unroll
    for (int j = 0; j < 3; ++j) {
        if (pjs[j] == 1) continue;
        #pragma unroll
        for (int pt = 0; pt < 2; ++pt) {
            const int d = pt * 32 + l31;
            #pragma unroll
            for (int g2 = 0; g2 < 4; ++g2)
                #pragma unroll
                for (int rr = 0; rr < 4; ++rr) {
                    const int o = obs[j] + rr + 4 * hi + 8 * g2;
                    const float v = acc[j][pt][g2 * 4 + rr] + bias[j][pt][g2][rr];
                    if (pjs[j] == 0) {
                        *(bf16_t*)(SM + o * 128 + d * 2) = (bf16_t)v;
                    } else {
                        *(bf16_t*)(SM + 32768 + d * 512 + ((o * 2) ^ ((d & 7) << 4))) = (bf16_t)v;
                    }
                }
        }
    }
    __syncthreads();
    {
        bf16_t* qp = q_ws + (size_t)bn * 4096 * 64;
        #pragma unroll
        for (int i = 0; i < 4; ++i) {
            const int c = i * 512 + tid;
            const int o = c >> 3, d8 = c & 7;
            uint4 v = *(const uint4*)(SM + c * 16);
            *(uint4*)(qp + (size_t)(o * 16 + h2) * 64 + d8 * 8) = v;
        }
        bf16_t* vp = vt2_ws + (size_t)bn * 64 * 4096 + h2 * 256;
        #pragma unroll
        for (int i = 0; i < 4; ++i) {
            const int c = i * 512 + tid;
            const int d = c >> 5, k = c & 31;
            uint4 v = *(const uint4*)(SM + 32768 + d * 512 + ((k * 16) ^ ((d & 7) << 4)));
            *(uint4*)(vp + (size_t)d * 4096 + k * 8) = v;
        }
    }
    __syncthreads();

    // pass 2: K -> [0,32K)
    #pragma unroll
    for (int j = 0; j < 3; ++j) {
        if (pjs[j] != 1) continue;
        #pragma unroll
        for (int pt = 0; pt < 2; ++pt) {
            const int d = pt * 32 + l31;
            #pragma unroll
            for (int g2 = 0; g2 < 4; ++g2)
                #pragma unroll
                for (int rr = 0; rr < 4; ++rr) {
                    const int o = obs[j] + rr + 4 * hi + 8 * g2;
                    *(bf16_t*)(SM + o * 128 + d * 2) =
                        (bf16_t)(acc[j][pt][g2 * 4 + rr] + bias[j][pt][g2][rr]);
                }
        }
    }
    __syncthreads();
    {
        const bf16_t* Rp = Rt + ((size_t)n * 4096 + h2 * 256) * 64;
        bf16_t* kp = k2_ws + ((size_t)bn * 4096 + h2 * 256) * 64;
        #pragma unroll
        for (int i = 0; i < 4; ++i) {
            const int c = i * 512 + tid;
            bf16x8 kv = *(const bf16x8*)(SM + c * 16);
            bf16x8 rv = *(const bf16x8*)(Rp + c * 8);
            bf16x8 res;
            #pragma unroll
            for (int ii = 0; ii < 8; ++ii)
                res[ii] = (__bf16)((float)kv[ii] + (float)rv[ii]);
            *(bf16x8*)(kp + c * 8) = res;
        }
    }
}

// =======================================================================================
// flash attention v7: ring-4 64KB, barrier per 2-tile PAIR (R8 loop shape at pair
// granularity). grid 512 (16 bn x 32 qb), block 256 = 4 waves, 32 q/wave,
// 2 blocks/CU = 2 waves/SIMD. Waves de-phase within a pair (no mid-pair resync).
// =======================================================================================
__global__ __launch_bounds__(256, 2)
void attn_kernel(const bf16_t* __restrict__ q_ws, const bf16_t* __restrict__ k_ws,
                 const bf16_t* __restrict__ vt_ws, float* __restrict__ out)
{
    const int tid  = threadIdx.x;
    const int wid  = tid >> 6;
    const int lane = tid & 63;
    const int l31  = lane & 31;
    const int hi   = lane >> 5;

    // bijective XCD swizzle: 512 blocks, 64/XCD = 2 bn per XCD (K/V L2-resident)
    const int wg  = blockIdx.x;
    const int swz = (wg & 7) * 64 + (wg >> 3);
    const int bn  = swz >> 5;
    const int qb  = swz & 31;
    const int b   = bn >> 2, n = bn & 3;

    __shared__ __align__(16) bf16_t Kt[4][64 * 64];   // ring-4, XOR-swizzled 16B units
    __shared__ __align__(16) bf16_t Vt[4][64 * 64];

    const bf16_t* Qb = q_ws  + (size_t)bn * S_SZ * HS;
    const bf16_t* Kb = k_ws  + (size_t)bn * S_SZ * HS;
    const bf16_t* Vb = vt_ws + (size_t)bn * HS * S_SZ;

    const int c0 = wid * 64 + lane;
    const int ra = c0 >> 3, ga = (c0 & 7) ^ (ra & 7);
    const bf16_t* ksrcA = Kb + ra * HS + ga * 8;
    const bf16_t* ksrcB = ksrcA + 32 * HS;
    const bf16_t* vsrcA = Vb + (size_t)ra * S_SZ + ga * 8;
    const bf16_t* vsrcB = vsrcA + (size_t)32 * S_SZ;

#define STAGE(buf, ts)                                                        \
    GLOAD_LDS(ksrcA + (size_t)(ts) * 64 * HS, &Kt[buf][wid * 512]);           \
    GLOAD_LDS(ksrcB + (size_t)(ts) * 64 * HS, &Kt[buf][2048 + wid * 512]);    \
    GLOAD_LDS(vsrcA + (ts) * 64,              &Vt[buf][wid * 512]);           \
    GLOAD_LDS(vsrcB + (ts) * 64,              &Vt[buf][2048 + wid * 512]);

    const int q = qb * 128 + wid * 32 + l31;
    bf16x8 qf[4];
    #pragma unroll
    for (int dk = 0; dk < 4; ++dk)
        qf[dk] = *(const bf16x8*)(Qb + (size_t)q * HS + dk * 16 + hi * 8);

    f32x16 oacc[2];
    f32x16 Z16;
    #pragma unroll
    for (int i = 0; i < 16; ++i) { oacc[0][i] = 0.f; oacc[1][i] = 0.f; Z16[i] = 0.f; }
    float lsum = 0.f;

    const int swzme = (l31 & 7) << 4;

#define TILE(BUF)                                                                      \
    { const char* Kb_ = (const char*)&Kt[BUF][0] + l31 * 128;                          \
      const char* Vb_ = (const char*)&Vt[BUF][0] + l31 * 128;                          \
      f32x16 sacc[2];                                                                  \
      __builtin_amdgcn_s_setprio(1);                                                   \
      _Pragma("unroll")                                                                \
      for (int hh = 0; hh < 2; ++hh) {                                                 \
          bf16x8 kf[4];                                                                \
          _Pragma("unroll")                                                            \
          for (int dk = 0; dk < 4; ++dk)                                               \
              kf[dk] = *(const bf16x8*)(Kb_ + hh * 4096 + (((2 * dk + hi) * 16) ^ swzme)); \
          sacc[hh] = __builtin_amdgcn_mfma_f32_32x32x16_bf16(kf[0], qf[0], Z16, 0, 0, 0);  \
          _Pragma("unroll")                                                            \
          for (int dk = 1; dk < 4; ++dk)                                               \
              sacc[hh] = __builtin_amdgcn_mfma_f32_32x32x16_bf16(kf[dk], qf[dk], sacc[hh], 0, 0, 0); \
      }                                                                                \
      __builtin_amdgcn_s_setprio(0);                                                   \
      u32 Wd[2][4][2];                                                                 \
      float ps[4] = {0.f, 0.f, 0.f, 0.f};                                              \
      _Pragma("unroll")                                                                \
      for (int hh = 0; hh < 2; ++hh)                                                   \
      _Pragma("unroll")                                                                \
      for (int c = 0; c < 4; ++c)                                                      \
      _Pragma("unroll")                                                                \
      for (int tt = 0; tt < 2; ++tt) {                                                 \
          float pa = __builtin_amdgcn_exp2f(sacc[hh][c * 4 + tt * 2]);                 \
          float pb = __builtin_amdgcn_exp2f(sacc[hh][c * 4 + tt * 2 + 1]);             \
          ps[c] += pa + pb;                                                            \
          u32 w_;                                                                      \
          asm("v_cvt_pk_bf16_f32 %0, %1, %2" : "=v"(w_) : "v"(pa), "v"(pb));           \
          Wd[hh][c][tt] = w_; }                                                        \
      lsum += (ps[0] + ps[1]) + (ps[2] + ps[3]);                                       \
      u32 F[4][4];                                                                     \
      _Pragma("unroll")                                                                \
      for (int hh = 0; hh < 2; ++hh)                                                   \
      _Pragma("unroll")                                                                \
      for (int pr = 0; pr < 2; ++pr)                                                   \
      _Pragma("unroll")                                                                \
      for (int tt = 0; tt < 2; ++tt) {                                                 \
          u32 a_ = Wd[hh][2 * pr][tt], b_ = Wd[hh][2 * pr + 1][tt];                    \
          asm("v_permlane32_swap_b32 %0, %1" : "+v"(a_), "+v"(b_));                    \
          F[2 * hh + pr][tt]     = a_;                                                 \
          F[2 * hh + pr][2 + tt] = b_; }                                               \
      __builtin_amdgcn_s_setprio(1);                                                   \
      _Pragma("unroll")                                                                \
      for (int dh = 0; dh < 2; ++dh)                                                   \
      _Pragma("unroll")                                                                \
      for (int kk = 0; kk < 4; ++kk) {                                                 \
          bf16x8 vf = *(const bf16x8*)(Vb_ + dh * 4096 + (((2 * kk + hi) * 16) ^ swzme)); \
          union { u32 u[4]; bf16x8 v; } pf;                                            \
          pf.u[0] = F[kk][0]; pf.u[1] = F[kk][1]; pf.u[2] = F[kk][2]; pf.u[3] = F[kk][3]; \
          oacc[dh] = __builtin_amdgcn_mfma_f32_32x32x16_bf16(vf, pf.v, oacc[dh], 0, 0, 0); } \
      __builtin_amdgcn_s_setprio(0); }

    // prologue: tiles 0,1 resident
    STAGE(0, 0); STAGE(1, 1);
    asm volatile("s_waitcnt vmcnt(0)" ::: "memory");
    __builtin_amdgcn_s_barrier();
    asm volatile("" ::: "memory");

    // pair loop: stage next pair, compute current pair, one drain+barrier per pair
    for (int t = 0; t < 64; t += 2) {
        { const int t2 = (t + 2 < 64) ? t + 2 : 63;
          const int t3 = (t + 3 < 64) ? t + 3 : 63;
          STAGE((t + 2) & 3, t2);
          STAGE((t + 3) & 3, t3); }
        TILE(t & 3);
        TILE((t + 1) & 3);
        asm volatile("s_waitcnt vmcnt(0)" ::: "memory");
        __builtin_amdgcn_s_barrier();
        asm volatile("" ::: "memory");
    }
#undef TILE
#undef STAGE

    // ---- epilogue ----
    float lt  = lsum + __shfl_xor(lsum, 32);
    float inv = 1.0f / lt;
    float* outp = out + (size_t)b * OUT_B_STRIDE + (size_t)q * 256 + n * 64;
    #pragma unroll
    for (int dh = 0; dh < 2; ++dh)
        #pragma unroll
        for (int g2 = 0; g2 < 4; ++g2) {
            f32x4 v4;
            #pragma unroll
            for (int r = 0; r < 4; ++r) v4[r] = oacc[dh][g2 * 4 + r] * inv;
            *(f32x4*)(outp + dh * 32 + g2 * 8 + hi * 4) = v4;
        }
}

extern "C" void kernel_launch(void* const* d_in, const int* in_sizes, int n_in,
                              void* d_out, int out_size, void* d_ws, size_t ws_size,
                              hipStream_t stream)
{
    const float* x     = (const float*)d_in[0];
    const float* wq    = (const float*)d_in[1];
    const float* bq    = (const float*)d_in[2];
    const float* wk    = (const float*)d_in[3];
    const float* bk    = (const float*)d_in[4];
    const float* wv    = (const float*)d_in[5];
    const float* bv    = (const float*)d_in[6];
    const float* rel_h = (const float*)d_in[7];
    const float* rel_w = (const float*)d_in[8];
    float* out = (float*)d_out;

    bf16_t* q_ws   = (bf16_t*)d_ws;
    bf16_t* k2_ws  = q_ws  + (size_t)16 * S_SZ * HS;
    bf16_t* vt2_ws = k2_ws + (size_t)16 * S_SZ * HS;

    // scratch in d_out's tail (dead after proj; attn overwrites all of out)
    bf16_t* end = (bf16_t*)d_out + (size_t)out_size * 2;
    bf16_t* Wl  = end - 196608;
    bf16_t* Wh  = Wl - 196608;
    bf16_t* Rt  = Wh - 1048576;

    prep_kernel<<<112, 256, 0, stream>>>(wq, wk, wv, rel_h, rel_w, Wh, Wl, Rt);
    proj_kernel<<<256, 512, 0, stream>>>(x, Wh, Wl, bq, bk, bv, Rt,
                                         q_ws, k2_ws, vt2_ws);
    attn_kernel<<<512, 256, 0, stream>>>(q_ws, k2_ws, vt2_ws, out);
}

// Round 15
// 129.911 us; speedup vs baseline: 1.3227x; 1.0052x over previous
//
#include <hip/hip_runtime.h>
#include <hip/hip_bf16.h>
#include <stdint.h>
#include <math.h>

typedef __bf16 bf16_t;
typedef __bf16 bf16x8 __attribute__((ext_vector_type(8)));
typedef float  f32x4  __attribute__((ext_vector_type(4)));
typedef float  f32x16 __attribute__((ext_vector_type(16)));
typedef unsigned int u32;

#define S_SZ 4096
#define HS   64
#define OUT_B_STRIDE (256 * 64 * 64)
#define LOG2E 1.4426950408889634f

// async global->LDS, 16B per lane, dest = wave-uniform base + lane*16
#define GLOAD_LDS(gsrc, ldst)                                                              \
    __builtin_amdgcn_global_load_lds((__attribute__((address_space(1))) void*)(void*)(gsrc), \
                                     (__attribute__((address_space(3))) void*)(void*)(ldst),  \
                                     16, 0, 0)

static __device__ __forceinline__ u32 pack2(__bf16 a, __bf16 b) {
    return (u32)__builtin_bit_cast(uint16_t, a) | ((u32)__builtin_bit_cast(uint16_t, b) << 16);
}

// =======================================================================================
// prep: blocks 0..47: W -> bf16 hi/lo (Q rows pre-scaled by log2e), coalesced.
//       blocks 48..111: R[n][t][d] = rel_h + rel_w (bf16), t = h2*256 + o, LDS-staged.
// =======================================================================================
__global__ __launch_bounds__(256)
void prep_kernel(const float* __restrict__ wq, const float* __restrict__ wk,
                 const float* __restrict__ wv, const float* __restrict__ rel_h,
                 const float* __restrict__ rel_w,
                 bf16_t* __restrict__ Wh, bf16_t* __restrict__ Wl,
                 bf16_t* __restrict__ Rt)
{
    const int blk = blockIdx.x;
    if (blk < 48) {
        const int base = blk * 4096;
        #pragma unroll
        for (int i = 0; i < 16; ++i) {
            const int e = base + i * 256 + threadIdx.x;
            const int o = e >> 8, c = e & 255;
            const float* src = o < 256 ? wq : (o < 512 ? wk : wv);
            float v = src[(size_t)(o & 255) * 256 + c];
            if (o < 256) v *= LOG2E;
            __bf16 h = (__bf16)v;
            Wh[e] = h;
            Wl[e] = (__bf16)(v - (float)h);
        }
    } else {
        const int rb = blk - 48;
        const int n = rb >> 4, h2 = rb & 15;
        __shared__ float rh[4096], rw[4096];
        for (int i = threadIdx.x; i < 4096; i += 256) {
            rh[i] = rel_h[n * 4096 + i];
            rw[i] = rel_w[n * 4096 + i];
        }
        __syncthreads();
        bf16_t* Rp = Rt + ((size_t)n * 4096 + h2 * 256) * 64;
        const int d0 = (threadIdx.x & 7) * 8;
        const int ob = threadIdx.x >> 3;
        #pragma unroll
        for (int i = 0; i < 8; ++i) {
            const int o  = i * 32 + ob;
            const int ih = (o & 3) * 16 + h2;
            const int iw = o >> 2;
            bf16x8 rv;
            #pragma unroll
            for (int dd = 0; dd < 8; ++dd)
                rv[dd] = (bf16_t)(rh[(d0 + dd) * 64 + ih] + rw[(d0 + dd) * 64 + iw]);
            *(bf16x8*)(Rp + (size_t)o * 64 + d0) = rv;
        }
    }
}

// =======================================================================================
// proj v2: ONE projection per block. grid 768 = (sub: 0=Q,1=K,2=V) x 4 b x 64 h,
// block 512 (8 waves, 1x 32-row tile each), 64KB LDS -> 2 blocks/CU = 4 waves/SIMD.
// Co-resident blocks overlap stage/K-loop/epilogue phases. Single-pass epilogue.
// =======================================================================================
__global__ __launch_bounds__(512, 4)
void proj_kernel(const float* __restrict__ x,
                 const bf16_t* __restrict__ Wh, const bf16_t* __restrict__ Wl,
                 const float* __restrict__ bq, const float* __restrict__ bk,
                 const float* __restrict__ bv, const bf16_t* __restrict__ Rt,
                 bf16_t* __restrict__ q_ws, bf16_t* __restrict__ k2_ws,
                 bf16_t* __restrict__ vt2_ws)
{
    const int bx  = blockIdx.x;
    const int sub = bx >> 8;          // 0=Q 1=K 2=V
    const int b   = (bx >> 6) & 3;
    const int h   = bx & 63;
    const int p0  = h * 64;
    const int n   = h & 3;
    const int h2  = h >> 2;
    const int bn  = b * 4 + n;
    const int tid = threadIdx.x;

    __shared__ __align__(16) char SM[65536];   // XT hi/lo -> reused for epilogue

    // ---- stage: transpose + hi/lo split of x[b][0..256][p0..p0+64] ----
    {
        const int cpair = tid & 127, pg = tid >> 7;
        const int c0 = cpair * 2;
        const float* x0 = x + ((size_t)b * 256 + c0) * 4096 + p0 + pg * 16;
        const int sb = (c0 >> 6) * 128;
        const int u  = (c0 >> 3) & 7;
        const int e2 = (c0 & 7) * 2;
        #pragma unroll
        for (int i4 = 0; i4 < 4; ++i4) {
            f32x4 ra = *(const f32x4*)(x0 + i4 * 4);
            f32x4 rb = *(const f32x4*)(x0 + 4096 + i4 * 4);
            #pragma unroll
            for (int i = 0; i < 4; ++i) {
                const int p = pg * 16 + i4 * 4 + i;
                __bf16 ha = (__bf16)ra[i], hb = (__bf16)rb[i];
                float  la = ra[i] - (float)ha, lb = rb[i] - (float)hb;
                const int off = p * 512 + sb + ((u ^ (p & 7)) * 16) + e2;
                *(u32*)(SM + off)         = pack2(ha, hb);
                *(u32*)(SM + 32768 + off) = pack2((__bf16)la, (__bf16)lb);
            }
        }
    }
    __syncthreads();

    const int wid = tid >> 6, lane = tid & 63, l31 = lane & 31, hi = lane >> 5;

    const int ob_ = wid * 32;                 // within-projection row base
    const int of  = sub * 256 + ob_;          // global W row
    const bf16_t* whp = Wh + (size_t)(of + l31) * 256 + hi * 8;
    const bf16_t* wlp = Wl + (size_t)(of + l31) * 256 + hi * 8;

    const char* XHp = SM + l31 * 512;
    const char* XLp = SM + 32768 + l31 * 512;

    f32x16 acc[2] = {};

    // W register double-buffer
    bf16x8 whC = *(const bf16x8*)(whp);
    bf16x8 wlC = *(const bf16x8*)(wlp);
    bf16x8 whN, wlN;

    #pragma unroll
    for (int ks = 0; ks < 16; ++ks) {
        if (ks < 15) {
            whN = *(const bf16x8*)(whp + (ks + 1) * 16);
            wlN = *(const bf16x8*)(wlp + (ks + 1) * 16);
        }
        const int rb_ = (ks >> 2) * 128 + ((((ks * 2 + hi) & 7) ^ (l31 & 7)) * 16);
        bf16x8 xh[2], xl[2];
        #pragma unroll
        for (int pt = 0; pt < 2; ++pt) {
            xh[pt] = *(const bf16x8*)(XHp + pt * 16384 + rb_);
            xl[pt] = *(const bf16x8*)(XLp + pt * 16384 + rb_);
        }
        #pragma unroll
        for (int pt = 0; pt < 2; ++pt) {
            acc[pt] = __builtin_amdgcn_mfma_f32_32x32x16_bf16(whC, xh[pt], acc[pt], 0, 0, 0);
            acc[pt] = __builtin_amdgcn_mfma_f32_32x32x16_bf16(whC, xl[pt], acc[pt], 0, 0, 0);
            acc[pt] = __builtin_amdgcn_mfma_f32_32x32x16_bf16(wlC, xh[pt], acc[pt], 0, 0, 0);
        }
        whC = whN; wlC = wlN;
    }
    __syncthreads();   // XT dead; SM reused below

    // bias (Q rows pre-scaled by log2e)
    const float* bp = sub == 0 ? bq : (sub == 1 ? bk : bv);
    f32x4 bv4[4];
    #pragma unroll
    for (int g2 = 0; g2 < 4; ++g2) {
        bv4[g2] = *(const f32x4*)(bp + ob_ + hi * 4 + g2 * 8);
        if (sub == 0) {
            #pragma unroll
            for (int i = 0; i < 4; ++i) bv4[g2][i] *= LOG2E;
        }
    }

    // ---- scatter to SM ----
    if (sub != 2) {
        // [o][d] layout (Q and K)
        #pragma unroll
        for (int pt = 0; pt < 2; ++pt) {
            const int d = pt * 32 + l31;
            #pragma unroll
            for (int g2 = 0; g2 < 4; ++g2)
                #pragma unroll
                for (int rr = 0; rr < 4; ++rr) {
                    const int o = ob_ + rr + 4 * hi + 8 * g2;
                    *(bf16_t*)(SM + o * 128 + d * 2) =
                        (bf16_t)(acc[pt][g2 * 4 + rr] + bv4[g2][rr]);
                }
        }
    } else {
        // [d][o] swizzled layout (V^T)
        #pragma unroll
        for (int pt = 0; pt < 2; ++pt) {
            const int d = pt * 32 + l31;
            #pragma unroll
            for (int g2 = 0; g2 < 4; ++g2)
                #pragma unroll
                for (int rr = 0; rr < 4; ++rr) {
                    const int o = ob_ + rr + 4 * hi + 8 * g2;
                    *(bf16_t*)(SM + d * 512 + ((o * 2) ^ ((d & 7) << 4))) =
                        (bf16_t)(acc[pt][g2 * 4 + rr] + bv4[g2][rr]);
                }
        }
    }
    __syncthreads();

    // ---- coalesced write-out (single purpose per block) ----
    if (sub == 0) {
        bf16_t* qp = q_ws + (size_t)bn * 4096 * 64;
        #pragma unroll
        for (int i = 0; i < 4; ++i) {
            const int c = i * 512 + tid;
            const int o = c >> 3, d8 = c & 7;
            uint4 v = *(const uint4*)(SM + c * 16);
            *(uint4*)(qp + (size_t)(o * 16 + h2) * 64 + d8 * 8) = v;
        }
    } else if (sub == 1) {
        const bf16_t* Rp = Rt + ((size_t)n * 4096 + h2 * 256) * 64;
        bf16_t* kp = k2_ws + ((size_t)bn * 4096 + h2 * 256) * 64;
        #pragma unroll
        for (int i = 0; i < 4; ++i) {
            const int c = i * 512 + tid;
            bf16x8 kv = *(const bf16x8*)(SM + c * 16);
            bf16x8 rv = *(const bf16x8*)(Rp + c * 8);
            bf16x8 res;
            #pragma unroll
            for (int ii = 0; ii < 8; ++ii)
                res[ii] = (__bf16)((float)kv[ii] + (float)rv[ii]);
            *(bf16x8*)(kp + c * 8) = res;
        }
    } else {
        bf16_t* vp = vt2_ws + (size_t)bn * 64 * 4096 + h2 * 256;
        #pragma unroll
        for (int i = 0; i < 4; ++i) {
            const int c = i * 512 + tid;
            const int d = c >> 5, k = c & 31;
            uint4 v = *(const uint4*)(SM + d * 512 + ((k * 16) ^ ((d & 7) << 4)));
            *(uint4*)(vp + (size_t)d * 4096 + k * 8) = v;
        }
    }
}

// =======================================================================================
// flash attention (R9 verbatim): T15 double-pipeline, 4-buffer ring, counted vmcnt(4),
// 1 barrier/iter. grid 512 (16 bn x 32 qb), block 256 = 4 waves, 2 blocks/CU.
// =======================================================================================
__global__ __launch_bounds__(256, 2)
void attn_kernel(const bf16_t* __restrict__ q_ws, const bf16_t* __restrict__ k_ws,
                 const bf16_t* __restrict__ vt_ws, float* __restrict__ out)
{
    const int tid  = threadIdx.x;
    const int wid  = tid >> 6;
    const int lane = tid & 63;
    const int l31  = lane & 31;
    const int hi   = lane >> 5;

    const int wg  = blockIdx.x;
    const int swz = (wg & 7) * 64 + (wg >> 3);
    const int bn  = swz >> 5;
    const int qb  = swz & 31;
    const int b   = bn >> 2, n = bn & 3;

    __shared__ __align__(16) bf16_t Kt[4][64 * 64];
    __shared__ __align__(16) bf16_t Vt[4][64 * 64];

    const bf16_t* Qb = q_ws  + (size_t)bn * S_SZ * HS;
    const bf16_t* Kb = k_ws  + (size_t)bn * S_SZ * HS;
    const bf16_t* Vb = vt_ws + (size_t)bn * HS * S_SZ;

    const int c0 = wid * 64 + lane;
    const int ra = c0 >> 3, ga = (c0 & 7) ^ (ra & 7);
    const bf16_t* ksrcA = Kb + ra * HS + ga * 8;
    const bf16_t* ksrcB = ksrcA + 32 * HS;
    const bf16_t* vsrcA = Vb + (size_t)ra * S_SZ + ga * 8;
    const bf16_t* vsrcB = vsrcA + (size_t)32 * S_SZ;

#define STAGE(buf, ts)                                                        \
    GLOAD_LDS(ksrcA + (size_t)(ts) * 64 * HS, &Kt[buf][wid * 512]);           \
    GLOAD_LDS(ksrcB + (size_t)(ts) * 64 * HS, &Kt[buf][2048 + wid * 512]);    \
    GLOAD_LDS(vsrcA + (ts) * 64,              &Vt[buf][wid * 512]);           \
    GLOAD_LDS(vsrcB + (ts) * 64,              &Vt[buf][2048 + wid * 512]);

    const int q = qb * 128 + wid * 32 + l31;
    bf16x8 qf[4];
    #pragma unroll
    for (int dk = 0; dk < 4; ++dk)
        qf[dk] = *(const bf16x8*)(Qb + (size_t)q * HS + dk * 16 + hi * 8);

    f32x16 oacc[2];
    f32x16 Z16;
    #pragma unroll
    for (int i = 0; i < 16; ++i) { oacc[0][i] = 0.f; oacc[1][i] = 0.f; Z16[i] = 0.f; }
    float lsum = 0.f;

    const int swzme = (l31 & 7) << 4;

#define QKPAIR(DST, BUF)                                                               \
    { const char* Kb_ = (const char*)&Kt[BUF][0] + l31 * 128;                          \
      __builtin_amdgcn_s_setprio(1);                                                   \
      _Pragma("unroll")                                                                \
      for (int hh = 0; hh < 2; ++hh) {                                                 \
          bf16x8 kf[4];                                                                \
          _Pragma("unroll")                                                            \
          for (int dk = 0; dk < 4; ++dk)                                               \
              kf[dk] = *(const bf16x8*)(Kb_ + hh * 4096 + (((2 * dk + hi) * 16) ^ swzme)); \
          DST[hh] = __builtin_amdgcn_mfma_f32_32x32x16_bf16(kf[0], qf[0], Z16, 0, 0, 0);   \
          _Pragma("unroll")                                                            \
          for (int dk = 1; dk < 4; ++dk)                                               \
              DST[hh] = __builtin_amdgcn_mfma_f32_32x32x16_bf16(kf[dk], qf[dk], DST[hh], 0, 0, 0); \
      }                                                                                \
      __builtin_amdgcn_s_setprio(0); }

#define EXPPV(SRC, VBUF)                                                               \
    { u32 Wd[2][4][2];                                                                 \
      float ps[4] = {0.f, 0.f, 0.f, 0.f};                                              \
      _Pragma("unroll")                                                                \
      for (int hh = 0; hh < 2; ++hh)                                                   \
      _Pragma("unroll")                                                                \
      for (int c = 0; c < 4; ++c)                                                      \
      _Pragma("unroll")                                                                \
      for (int tt = 0; tt < 2; ++tt) {                                                 \
          float pa = __builtin_amdgcn_exp2f(SRC[hh][c * 4 + tt * 2]);                  \
          float pb = __builtin_amdgcn_exp2f(SRC[hh][c * 4 + tt * 2 + 1]);              \
          ps[c] += pa + pb;                                                            \
          u32 w_;                                                                      \
          asm("v_cvt_pk_bf16_f32 %0, %1, %2" : "=v"(w_) : "v"(pa), "v"(pb));           \
          Wd[hh][c][tt] = w_; }                                                        \
      lsum += (ps[0] + ps[1]) + (ps[2] + ps[3]);                                       \
      u32 F[4][4];                                                                     \
      _Pragma("unroll")                                                                \
      for (int hh = 0; hh < 2; ++hh)                                                   \
      _Pragma("unroll")                                                                \
      for (int pr = 0; pr < 2; ++pr)                                                   \
      _Pragma("unroll")                                                                \
      for (int tt = 0; tt < 2; ++tt) {                                                 \
          u32 a_ = Wd[hh][2 * pr][tt], b_ = Wd[hh][2 * pr + 1][tt];                    \
          asm("v_permlane32_swap_b32 %0, %1" : "+v"(a_), "+v"(b_));                    \
          F[2 * hh + pr][tt]     = a_;                                                 \
          F[2 * hh + pr][2 + tt] = b_; }                                               \
      const char* Vb_ = (const char*)&Vt[VBUF][0] + l31 * 128;                         \
      __builtin_amdgcn_s_setprio(1);                                                   \
      _Pragma("unroll")                                                                \
      for (int dh = 0; dh < 2; ++dh)                                                   \
      _Pragma("unroll")                                                                \
      for (int kk = 0; kk < 4; ++kk) {                                                 \
          bf16x8 vf = *(const bf16x8*)(Vb_ + dh * 4096 + (((2 * kk + hi) * 16) ^ swzme)); \
          union { u32 u[4]; bf16x8 v; } pf;                                            \
          pf.u[0] = F[kk][0]; pf.u[1] = F[kk][1]; pf.u[2] = F[kk][2]; pf.u[3] = F[kk][3]; \
          oacc[dh] = __builtin_amdgcn_mfma_f32_32x32x16_bf16(vf, pf.v, oacc[dh], 0, 0, 0); } \
      __builtin_amdgcn_s_setprio(0); }

#define ITER(U, SC, SN)                                                                \
    { asm volatile("s_waitcnt vmcnt(4)" ::: "memory");                                 \
      __builtin_amdgcn_s_barrier();                                                    \
      asm volatile("" ::: "memory");                                                   \
      { const int t_ = tb + (U);                                                       \
        const int ts_ = (t_ + 3 > 63) ? 63 : t_ + 3;                                   \
        STAGE(((U) + 3) & 3, ts_); }                                                   \
      QKPAIR(SN, ((U) + 1) & 3);                                                       \
      EXPPV(SC, (U) & 3); }

    STAGE(0, 0); STAGE(1, 1); STAGE(2, 2);
    asm volatile("s_waitcnt vmcnt(8)" ::: "memory");
    __builtin_amdgcn_s_barrier();
    asm volatile("" ::: "memory");

    f32x16 S0[2], S1[2];
    QKPAIR(S0, 0);

    for (int tb = 0; tb < 64; tb += 4) {
        ITER(0, S0, S1);
        ITER(1, S1, S0);
        ITER(2, S0, S1);
        ITER(3, S1, S0);
    }
#undef ITER
#undef EXPPV
#undef QKPAIR
#undef STAGE

    float lt  = lsum + __shfl_xor(lsum, 32);
    float inv = 1.0f / lt;
    float* outp = out + (size_t)b * OUT_B_STRIDE + (size_t)q * 256 + n * 64;
    #pragma unroll
    for (int dh = 0; dh < 2; ++dh)
        #pragma unroll
        for (int g2 = 0; g2 < 4; ++g2) {
            f32x4 v4;
            #pragma unroll
            for (int r = 0; r < 4; ++r) v4[r] = oacc[dh][g2 * 4 + r] * inv;
            *(f32x4*)(outp + dh * 32 + g2 * 8 + hi * 4) = v4;
        }
}

extern "C" void kernel_launch(void* const* d_in, const int* in_sizes, int n_in,
                              void* d_out, int out_size, void* d_ws, size_t ws_size,
                              hipStream_t stream)
{
    const float* x     = (const float*)d_in[0];
    const float* wq    = (const float*)d_in[1];
    const float* bq    = (const float*)d_in[2];
    const float* wk    = (const float*)d_in[3];
    const float* bk    = (const float*)d_in[4];
    const float* wv    = (const float*)d_in[5];
    const float* bv    = (const float*)d_in[6];
    const float* rel_h = (const float*)d_in[7];
    const float* rel_w = (const float*)d_in[8];
    float* out = (float*)d_out;

    bf16_t* q_ws   = (bf16_t*)d_ws;
    bf16_t* k2_ws  = q_ws  + (size_t)16 * S_SZ * HS;
    bf16_t* vt2_ws = k2_ws + (size_t)16 * S_SZ * HS;

    // scratch in d_out's tail (dead after proj; attn overwrites all of out)
    bf16_t* end = (bf16_t*)d_out + (size_t)out_size * 2;
    bf16_t* Wl  = end - 196608;
    bf16_t* Wh  = Wl - 196608;
    bf16_t* Rt  = Wh - 1048576;

    prep_kernel<<<112, 256, 0, stream>>>(wq, wk, wv, rel_h, rel_w, Wh, Wl, Rt);
    proj_kernel<<<768, 512, 0, stream>>>(x, Wh, Wl, bq, bk, bv, Rt,
                                         q_ws, k2_ws, vt2_ws);
    attn_kernel<<<512, 256, 0, stream>>>(q_ws, k2_ws, vt2_ws, out);
}

// Round 16
// 123.107 us; speedup vs baseline: 1.3958x; 1.0553x over previous
//
#include <hip/hip_runtime.h>
#include <hip/hip_bf16.h>
#include <stdint.h>
#include <math.h>

typedef __bf16 bf16_t;
typedef __bf16 bf16x8 __attribute__((ext_vector_type(8)));
typedef float  f32x4  __attribute__((ext_vector_type(4)));
typedef float  f32x16 __attribute__((ext_vector_type(16)));
typedef unsigned int u32;

#define S_SZ 4096
#define HS   64
#define OUT_B_STRIDE (256 * 64 * 64)
#define LOG2E 1.4426950408889634f

// async global->LDS, 16B per lane, dest = wave-uniform base + lane*16
#define GLOAD_LDS(gsrc, ldst)                                                              \
    __builtin_amdgcn_global_load_lds((__attribute__((address_space(1))) void*)(void*)(gsrc), \
                                     (__attribute__((address_space(3))) void*)(void*)(ldst),  \
                                     16, 0, 0)

static __device__ __forceinline__ u32 pack2(__bf16 a, __bf16 b) {
    return (u32)__builtin_bit_cast(uint16_t, a) | ((u32)__builtin_bit_cast(uint16_t, b) << 16);
}

// =======================================================================================
// prep: blocks 0..47: W -> bf16 hi/lo in FRAGMENT-MAJOR layout (Q rows pre-scaled by
//   log2e): chunk (o>>5, c>>4) holds 64 lanes x 8 elems; lane = ((c>>3)&1)*32 + (o&31),
//   elem j = c&7. Proj reads become lane-coalesced (base + lane*16).
//       blocks 48..111: R[n][t][d] = rel_h + rel_w (bf16), t = h2*256 + o, LDS-staged.
// =======================================================================================
__global__ __launch_bounds__(256)
void prep_kernel(const float* __restrict__ wq, const float* __restrict__ wk,
                 const float* __restrict__ wv, const float* __restrict__ rel_h,
                 const float* __restrict__ rel_w,
                 bf16_t* __restrict__ Wh, bf16_t* __restrict__ Wl,
                 bf16_t* __restrict__ Rt)
{
    const int blk = blockIdx.x;
    if (blk < 48) {
        const int base = blk * 4096;
        #pragma unroll
        for (int i = 0; i < 16; ++i) {
            const int e = base + i * 256 + threadIdx.x;
            const int o = e >> 8, c = e & 255;
            const float* src = o < 256 ? wq : (o < 512 ? wk : wv);
            float v = src[(size_t)(o & 255) * 256 + c];
            if (o < 256) v *= LOG2E;
            __bf16 h = (__bf16)v;
            // fragment-major index
            const int idx = ((o >> 5) * 16 + (c >> 4)) * 512 +
                            (((c >> 3) & 1) * 32 + (o & 31)) * 8 + (c & 7);
            Wh[idx] = h;
            Wl[idx] = (__bf16)(v - (float)h);
        }
    } else {
        const int rb = blk - 48;
        const int n = rb >> 4, h2 = rb & 15;
        __shared__ float rh[4096], rw[4096];
        for (int i = threadIdx.x; i < 4096; i += 256) {
            rh[i] = rel_h[n * 4096 + i];
            rw[i] = rel_w[n * 4096 + i];
        }
        __syncthreads();
        bf16_t* Rp = Rt + ((size_t)n * 4096 + h2 * 256) * 64;
        const int d0 = (threadIdx.x & 7) * 8;
        const int ob = threadIdx.x >> 3;
        #pragma unroll
        for (int i = 0; i < 8; ++i) {
            const int o  = i * 32 + ob;
            const int ih = (o & 3) * 16 + h2;
            const int iw = o >> 2;
            bf16x8 rv;
            #pragma unroll
            for (int dd = 0; dd < 8; ++dd)
                rv[dd] = (bf16_t)(rh[(d0 + dd) * 64 + ih] + rw[(d0 + dd) * 64 + iw]);
            *(bf16x8*)(Rp + (size_t)o * 64 + d0) = rv;
        }
    }
}

// =======================================================================================
// proj (R9 joint-QKV, 64KB LDS): bf16 MFMA, 3-product hi/lo split, W register dbuf,
// FRAGMENT-MAJOR W reads (lane-coalesced), two-pass coalesced epilogue.
// grid 256, block 512 (8 waves).
// =======================================================================================
__global__ __launch_bounds__(512, 2)
void proj_kernel(const float* __restrict__ x,
                 const bf16_t* __restrict__ Wh, const bf16_t* __restrict__ Wl,
                 const float* __restrict__ bq, const float* __restrict__ bk,
                 const float* __restrict__ bv, const bf16_t* __restrict__ Rt,
                 bf16_t* __restrict__ q_ws, bf16_t* __restrict__ k2_ws,
                 bf16_t* __restrict__ vt2_ws)
{
    const int bx = blockIdx.x;
    const int b  = bx >> 6;
    const int h  = bx & 63;
    const int p0 = h * 64;
    const int n  = h & 3;
    const int h2 = h >> 2;
    const int bn = b * 4 + n;
    const int tid = threadIdx.x;

    __shared__ __align__(16) char SM[65536];

    {
        const int cpair = tid & 127, pg = tid >> 7;
        const int c0 = cpair * 2;
        const float* x0 = x + ((size_t)b * 256 + c0) * 4096 + p0 + pg * 16;
        const int sub = (c0 >> 6) * 128;
        const int u   = (c0 >> 3) & 7;
        const int e2  = (c0 & 7) * 2;
        #pragma unroll
        for (int i4 = 0; i4 < 4; ++i4) {
            f32x4 ra = *(const f32x4*)(x0 + i4 * 4);
            f32x4 rb = *(const f32x4*)(x0 + 4096 + i4 * 4);
            #pragma unroll
            for (int i = 0; i < 4; ++i) {
                const int p = pg * 16 + i4 * 4 + i;
                __bf16 ha = (__bf16)ra[i], hb = (__bf16)rb[i];
                float  la = ra[i] - (float)ha, lb = rb[i] - (float)hb;
                const int off = p * 512 + sub + ((u ^ (p & 7)) * 16) + e2;
                *(u32*)(SM + off)         = pack2(ha, hb);
                *(u32*)(SM + 32768 + off) = pack2((__bf16)la, (__bf16)lb);
            }
        }
    }
    __syncthreads();

    const int wid = tid >> 6, lane = tid & 63, l31 = lane & 31, hi = lane >> 5;

    int obs[3], pjs[3];
    const bf16_t* whf[3];
    const bf16_t* wlf[3];
    #pragma unroll
    for (int j = 0; j < 3; ++j) {
        const int of = (wid * 3 + j) * 32;          // 32-aligned: row tile = wid*3+j
        pjs[j] = of >> 8;
        obs[j] = of & 255;
        whf[j] = Wh + (size_t)(wid * 3 + j) * 16 * 512 + lane * 8;
        wlf[j] = Wl + (size_t)(wid * 3 + j) * 16 * 512 + lane * 8;
    }

    const char* XHp = SM + l31 * 512;
    const char* XLp = SM + 32768 + l31 * 512;

    f32x16 acc[3][2] = {};

    // W register double-buffer (fragment-major: chunk stride 512 elems, lane-coalesced)
    bf16x8 whC[3], wlC[3], whN[3], wlN[3];
    #pragma unroll
    for (int j = 0; j < 3; ++j) {
        whC[j] = *(const bf16x8*)(whf[j]);
        wlC[j] = *(const bf16x8*)(wlf[j]);
    }

    #pragma unroll
    for (int ks = 0; ks < 16; ++ks) {
        if (ks < 15) {
            #pragma unroll
            for (int j = 0; j < 3; ++j) {
                whN[j] = *(const bf16x8*)(whf[j] + (ks + 1) * 512);
                wlN[j] = *(const bf16x8*)(wlf[j] + (ks + 1) * 512);
            }
        }
        const int rb_ = (ks >> 2) * 128 + ((((ks * 2 + hi) & 7) ^ (l31 & 7)) * 16);
        bf16x8 xh[2], xl[2];
        #pragma unroll
        for (int pt = 0; pt < 2; ++pt) {
            xh[pt] = *(const bf16x8*)(XHp + pt * 16384 + rb_);
            xl[pt] = *(const bf16x8*)(XLp + pt * 16384 + rb_);
        }
        #pragma unroll
        for (int j = 0; j < 3; ++j)
            #pragma unroll
            for (int pt = 0; pt < 2; ++pt) {
                acc[j][pt] = __builtin_amdgcn_mfma_f32_32x32x16_bf16(whC[j], xh[pt], acc[j][pt], 0, 0, 0);
                acc[j][pt] = __builtin_amdgcn_mfma_f32_32x32x16_bf16(whC[j], xl[pt], acc[j][pt], 0, 0, 0);
                acc[j][pt] = __builtin_amdgcn_mfma_f32_32x32x16_bf16(wlC[j], xh[pt], acc[j][pt], 0, 0, 0);
            }
        #pragma unroll
        for (int j = 0; j < 3; ++j) { whC[j] = whN[j]; wlC[j] = wlN[j]; }
    }
    __syncthreads();

    f32x4 bias[3][2][4];
    #pragma unroll
    for (int j = 0; j < 3; ++j) {
        const float* bp = pjs[j] == 0 ? bq : (pjs[j] == 1 ? bk : bv);
        #pragma unroll
        for (int g2 = 0; g2 < 4; ++g2) {
            f32x4 v = *(const f32x4*)(bp + obs[j] + hi * 4 + g2 * 8);
            if (pjs[j] == 0) {
                #pragma unroll
                for (int i = 0; i < 4; ++i) v[i] *= LOG2E;
            }
            bias[j][0][g2] = v;  bias[j][1][g2] = v;
        }
    }

    // pass 1: Q -> [0,32K), V -> [32,64K)
    #pragma unroll
    for (int j = 0; j < 3; ++j) {
        if (pjs[j] == 1) continue;
        #pragma unroll
        for (int pt = 0; pt < 2; ++pt) {
            const int d = pt * 32 + l31;
            #pragma unroll
            for (int g2 = 0; g2 < 4; ++g2)
                #pragma unroll
                for (int rr = 0; rr < 4; ++rr) {
                    const int o = obs[j] + rr + 4 * hi + 8 * g2;
                    const float v = acc[j][pt][g2 * 4 + rr] + bias[j][pt][g2][rr];
                    if (pjs[j] == 0) {
                        *(bf16_t*)(SM + o * 128 + d * 2) = (bf16_t)v;
                    } else {
                        *(bf16_t*)(SM + 32768 + d * 512 + ((o * 2) ^ ((d & 7) << 4))) = (bf16_t)v;
                    }
                }
        }
    }
    __syncthreads();
    {
        bf16_t* qp = q_ws + (size_t)bn * 4096 * 64;
        #pragma unroll
        for (int i = 0; i < 4; ++i) {
            const int c = i * 512 + tid;
            const int o = c >> 3, d8 = c & 7;
            uint4 v = *(const uint4*)(SM + c * 16);
            *(uint4*)(qp + (size_t)(o * 16 + h2) * 64 + d8 * 8) = v;
        }
        bf16_t* vp = vt2_ws + (size_t)bn * 64 * 4096 + h2 * 256;
        #pragma unroll
        for (int i = 0; i < 4; ++i) {
            const int c = i * 512 + tid;
            const int d = c >> 5, k = c & 31;
            uint4 v = *(const uint4*)(SM + 32768 + d * 512 + ((k * 16) ^ ((d & 7) << 4)));
            *(uint4*)(vp + (size_t)d * 4096 + k * 8) = v;
        }
    }
    __syncthreads();

    // pass 2: K -> [0,32K)
    #pragma unroll
    for (int j = 0; j < 3; ++j) {
        if (pjs[j] != 1) continue;
        #pragma unroll
        for (int pt = 0; pt < 2; ++pt) {
            const int d = pt * 32 + l31;
            #pragma unroll
            for (int g2 = 0; g2 < 4; ++g2)
                #pragma unroll
                for (int rr = 0; rr < 4; ++rr) {
                    const int o = obs[j] + rr + 4 * hi + 8 * g2;
                    *(bf16_t*)(SM + o * 128 + d * 2) =
                        (bf16_t)(acc[j][pt][g2 * 4 + rr] + bias[j][pt][g2][rr]);
                }
        }
    }
    __syncthreads();
    {
        const bf16_t* Rp = Rt + ((size_t)n * 4096 + h2 * 256) * 64;
        bf16_t* kp = k2_ws + ((size_t)bn * 4096 + h2 * 256) * 64;
        #pragma unroll
        for (int i = 0; i < 4; ++i) {
            const int c = i * 512 + tid;
            bf16x8 kv = *(const bf16x8*)(SM + c * 16);
            bf16x8 rv = *(const bf16x8*)(Rp + c * 8);
            bf16x8 res;
            #pragma unroll
            for (int ii = 0; ii < 8; ++ii)
                res[ii] = (__bf16)((float)kv[ii] + (float)rv[ii]);
            *(bf16x8*)(kp + c * 8) = res;
        }
    }
}

// =======================================================================================
// flash attention (R9 verbatim): T15 double-pipeline, 4-buffer ring, counted vmcnt(4),
// 1 barrier/iter. grid 512 (16 bn x 32 qb), block 256 = 4 waves, 2 blocks/CU.
// =======================================================================================
__global__ __launch_bounds__(256, 2)
void attn_kernel(const bf16_t* __restrict__ q_ws, const bf16_t* __restrict__ k_ws,
                 const bf16_t* __restrict__ vt_ws, float* __restrict__ out)
{
    const int tid  = threadIdx.x;
    const int wid  = tid >> 6;
    const int lane = tid & 63;
    const int l31  = lane & 31;
    const int hi   = lane >> 5;

    const int wg  = blockIdx.x;
    const int swz = (wg & 7) * 64 + (wg >> 3);
    const int bn  = swz >> 5;
    const int qb  = swz & 31;
    const int b   = bn >> 2, n = bn & 3;

    __shared__ __align__(16) bf16_t Kt[4][64 * 64];
    __shared__ __align__(16) bf16_t Vt[4][64 * 64];

    const bf16_t* Qb = q_ws  + (size_t)bn * S_SZ * HS;
    const bf16_t* Kb = k_ws  + (size_t)bn * S_SZ * HS;
    const bf16_t* Vb = vt_ws + (size_t)bn * HS * S_SZ;

    const int c0 = wid * 64 + lane;
    const int ra = c0 >> 3, ga = (c0 & 7) ^ (ra & 7);
    const bf16_t* ksrcA = Kb + ra * HS + ga * 8;
    const bf16_t* ksrcB = ksrcA + 32 * HS;
    const bf16_t* vsrcA = Vb + (size_t)ra * S_SZ + ga * 8;
    const bf16_t* vsrcB = vsrcA + (size_t)32 * S_SZ;

#define STAGE(buf, ts)                                                        \
    GLOAD_LDS(ksrcA + (size_t)(ts) * 64 * HS, &Kt[buf][wid * 512]);           \
    GLOAD_LDS(ksrcB + (size_t)(ts) * 64 * HS, &Kt[buf][2048 + wid * 512]);    \
    GLOAD_LDS(vsrcA + (ts) * 64,              &Vt[buf][wid * 512]);           \
    GLOAD_LDS(vsrcB + (ts) * 64,              &Vt[buf][2048 + wid * 512]);

    const int q = qb * 128 + wid * 32 + l31;
    bf16x8 qf[4];
    #pragma unroll
    for (int dk = 0; dk < 4; ++dk)
        qf[dk] = *(const bf16x8*)(Qb + (size_t)q * HS + dk * 16 + hi * 8);

    f32x16 oacc[2];
    f32x16 Z16;
    #pragma unroll
    for (int i = 0; i < 16; ++i) { oacc[0][i] = 0.f; oacc[1][i] = 0.f; Z16[i] = 0.f; }
    float lsum = 0.f;

    const int swzme = (l31 & 7) << 4;

#define QKPAIR(DST, BUF)                                                               \
    { const char* Kb_ = (const char*)&Kt[BUF][0] + l31 * 128;                          \
      __builtin_amdgcn_s_setprio(1);                                                   \
      _Pragma("unroll")                                                                \
      for (int hh = 0; hh < 2; ++hh) {                                                 \
          bf16x8 kf[4];                                                                \
          _Pragma("unroll")                                                            \
          for (int dk = 0; dk < 4; ++dk)                                               \
              kf[dk] = *(const bf16x8*)(Kb_ + hh * 4096 + (((2 * dk + hi) * 16) ^ swzme)); \
          DST[hh] = __builtin_amdgcn_mfma_f32_32x32x16_bf16(kf[0], qf[0], Z16, 0, 0, 0);   \
          _Pragma("unroll")                                                            \
          for (int dk = 1; dk < 4; ++dk)                                               \
              DST[hh] = __builtin_amdgcn_mfma_f32_32x32x16_bf16(kf[dk], qf[dk], DST[hh], 0, 0, 0); \
      }                                                                                \
      __builtin_amdgcn_s_setprio(0); }

#define EXPPV(SRC, VBUF)                                                               \
    { u32 Wd[2][4][2];                                                                 \
      float ps[4] = {0.f, 0.f, 0.f, 0.f};                                              \
      _Pragma("unroll")                                                                \
      for (int hh = 0; hh < 2; ++hh)                                                   \
      _Pragma("unroll")                                                                \
      for (int c = 0; c < 4; ++c)                                                      \
      _Pragma("unroll")                                                                \
      for (int tt = 0; tt < 2; ++tt) {                                                 \
          float pa = __builtin_amdgcn_exp2f(SRC[hh][c * 4 + tt * 2]);                  \
          float pb = __builtin_amdgcn_exp2f(SRC[hh][c * 4 + tt * 2 + 1]);              \
          ps[c] += pa + pb;                                                            \
          u32 w_;                                                                      \
          asm("v_cvt_pk_bf16_f32 %0, %1, %2" : "=v"(w_) : "v"(pa), "v"(pb));           \
          Wd[hh][c][tt] = w_; }                                                        \
      lsum += (ps[0] + ps[1]) + (ps[2] + ps[3]);                                       \
      u32 F[4][4];                                                                     \
      _Pragma("unroll")                                                                \
      for (int hh = 0; hh < 2; ++hh)                                                   \
      _Pragma("unroll")                                                                \
      for (int pr = 0; pr < 2; ++pr)                                                   \
      _Pragma("unroll")                                                                \
      for (int tt = 0; tt < 2; ++tt) {                                                 \
          u32 a_ = Wd[hh][2 * pr][tt], b_ = Wd[hh][2 * pr + 1][tt];                    \
          asm("v_permlane32_swap_b32 %0, %1" : "+v"(a_), "+v"(b_));                    \
          F[2 * hh + pr][tt]     = a_;                                                 \
          F[2 * hh + pr][2 + tt] = b_; }                                               \
      const char* Vb_ = (const char*)&Vt[VBUF][0] + l31 * 128;                         \
      __builtin_amdgcn_s_setprio(1);                                                   \
      _Pragma("unroll")                                                                \
      for (int dh = 0; dh < 2; ++dh)                                                   \
      _Pragma("unroll")                                                                \
      for (int kk = 0; kk < 4; ++kk) {                                                 \
          bf16x8 vf = *(const bf16x8*)(Vb_ + dh * 4096 + (((2 * kk + hi) * 16) ^ swzme)); \
          union { u32 u[4]; bf16x8 v; } pf;                                            \
          pf.u[0] = F[kk][0]; pf.u[1] = F[kk][1]; pf.u[2] = F[kk][2]; pf.u[3] = F[kk][3]; \
          oacc[dh] = __builtin_amdgcn_mfma_f32_32x32x16_bf16(vf, pf.v, oacc[dh], 0, 0, 0); } \
      __builtin_amdgcn_s_setprio(0); }

#define ITER(U, SC, SN)                                                                \
    { asm volatile("s_waitcnt vmcnt(4)" ::: "memory");                                 \
      __builtin_amdgcn_s_barrier();                                                    \
      asm volatile("" ::: "memory");                                                   \
      { const int t_ = tb + (U);                                                       \
        const int ts_ = (t_ + 3 > 63) ? 63 : t_ + 3;                                   \
        STAGE(((U) + 3) & 3, ts_); }                                                   \
      QKPAIR(SN, ((U) + 1) & 3);                                                       \
      EXPPV(SC, (U) & 3); }

    STAGE(0, 0); STAGE(1, 1); STAGE(2, 2);
    asm volatile("s_waitcnt vmcnt(8)" ::: "memory");
    __builtin_amdgcn_s_barrier();
    asm volatile("" ::: "memory");

    f32x16 S0[2], S1[2];
    QKPAIR(S0, 0);

    for (int tb = 0; tb < 64; tb += 4) {
        ITER(0, S0, S1);
        ITER(1, S1, S0);
        ITER(2, S0, S1);
        ITER(3, S1, S0);
    }
#undef ITER
#undef EXPPV
#undef QKPAIR
#undef STAGE

    float lt  = lsum + __shfl_xor(lsum, 32);
    float inv = 1.0f / lt;
    float* outp = out + (size_t)b * OUT_B_STRIDE + (size_t)q * 256 + n * 64;
    #pragma unroll
    for (int dh = 0; dh < 2; ++dh)
        #pragma unroll
        for (int g2 = 0; g2 < 4; ++g2) {
            f32x4 v4;
            #pragma unroll
            for (int r = 0; r < 4; ++r) v4[r] = oacc[dh][g2 * 4 + r] * inv;
            *(f32x4*)(outp + dh * 32 + g2 * 8 + hi * 4) = v4;
        }
}

extern "C" void kernel_launch(void* const* d_in, const int* in_sizes, int n_in,
                              void* d_out, int out_size, void* d_ws, size_t ws_size,
                              hipStream_t stream)
{
    const float* x     = (const float*)d_in[0];
    const float* wq    = (const float*)d_in[1];
    const float* bq    = (const float*)d_in[2];
    const float* wk    = (const float*)d_in[3];
    const float* bk    = (const float*)d_in[4];
    const float* wv    = (const float*)d_in[5];
    const float* bv    = (const float*)d_in[6];
    const float* rel_h = (const float*)d_in[7];
    const float* rel_w = (const float*)d_in[8];
    float* out = (float*)d_out;

    bf16_t* q_ws   = (bf16_t*)d_ws;
    bf16_t* k2_ws  = q_ws  + (size_t)16 * S_SZ * HS;
    bf16_t* vt2_ws = k2_ws + (size_t)16 * S_SZ * HS;

    // scratch in d_out's tail (dead after proj; attn overwrites all of out)
    bf16_t* end = (bf16_t*)d_out + (size_t)out_size * 2;
    bf16_t* Wl  = end - 196608;
    bf16_t* Wh  = Wl - 196608;
    bf16_t* Rt  = Wh - 1048576;

    prep_kernel<<<112, 256, 0, stream>>>(wq, wk, wv, rel_h, rel_w, Wh, Wl, Rt);
    proj_kernel<<<256, 512, 0, stream>>>(x, Wh, Wl, bq, bk, bv, Rt,
                                         q_ws, k2_ws, vt2_ws);
    attn_kernel<<<512, 256, 0, stream>>>(q_ws, k2_ws, vt2_ws, out);
}